// Round 4
// baseline (241.815 us; speedup 1.0000x reference)
//
#include <hip/hip_runtime.h>
#include <hip/hip_bf16.h>

#define BDIM 4096
#define DDIM 1024
#define NPAIRS 5
#define TW 16            // 4096/256 tiles per side
#define KT 16            // 1024/64 K-tiles
#define RSH 8192         // shorts per 256x32 region

typedef __attribute__((ext_vector_type(8))) short short8;
typedef __attribute__((ext_vector_type(4))) float floatx4;

__device__ __forceinline__ void gload16(const void* g, void* l) {
    __builtin_amdgcn_global_load_lds((const __attribute__((address_space(1))) void*)g,
                                     (__attribute__((address_space(3))) void*)l, 16, 0, 0);
}

__device__ __forceinline__ unsigned short f2bf(float f) {
    unsigned u = __float_as_uint(f);
    u = (u + 0x7FFFu + ((u >> 16) & 1u)) >> 16;   // RNE f32->bf16
    return (unsigned short)u;
}

// ---------------- cast f32 -> bf16, 4 matrices ----------------
__global__ void cast_kernel(const float* __restrict__ t, const float* __restrict__ im,
                            const float* __restrict__ au, const float* __restrict__ de,
                            short* __restrict__ out) {
    const float* src;
    switch (blockIdx.y) {
        case 0: src = t; break;
        case 1: src = im; break;
        case 2: src = au; break;
        default: src = de; break;
    }
    short* dst = out + (size_t)blockIdx.y * (BDIM * DDIM);
    int idx = (blockIdx.x * 256 + threadIdx.x) * 8;
    float4 f0 = *(const float4*)(src + idx);
    float4 f1 = *(const float4*)(src + idx + 4);
    short8 r;
    r[0] = (short)f2bf(f0.x); r[1] = (short)f2bf(f0.y);
    r[2] = (short)f2bf(f0.z); r[3] = (short)f2bf(f0.w);
    r[4] = (short)f2bf(f1.x); r[5] = (short)f2bf(f1.y);
    r[6] = (short)f2bf(f1.z); r[7] = (short)f2bf(f1.w);
    *(short8*)(dst + idx) = r;
}

// ---- stage one 256x32 region: linear LDS dest, inverse-swizzled global source.
// Linear byte off = i*8192 + w*1024 + l*16 -> row = i*128 + w*16 + (l>>2), phys slot = l&3.
// Logical k-chunk at phys slot p of row r is p ^ ((r>>1)&3) -> source kof = (l&3)^((l>>3)&3).
// Exactly 2 vmcnt ops per call (the pipeline vmcnt ledger counts these).
__device__ __forceinline__ void stage_region(const short* __restrict__ gsrc, short* reg,
                                             int w, int l, int k0) {
    const int r0 = w * 16 + (l >> 2);
    const int kof = ((l & 3) ^ ((l >> 3) & 3)) * 8;
#pragma unroll
    for (int i = 0; i < 2; ++i) {
        gload16(gsrc + (size_t)(i * 128 + r0) * DDIM + k0 + kof,
                (char*)reg + i * 8192 + w * 1024 + l * 16);
    }
}

// swizzled ds_read of an 8-bf16 fragment at logical (row, 16B-slot hi) in a 256x32 region.
// 64B rows, phys slot = hi ^ ((row>>1)&3): 2 lanes per 4-bank group = free (m136).
__device__ __forceinline__ short8 ldsfrag32(const short* reg, int row, int hi) {
    return *(const short8*)((const char*)reg + row * 64 + ((hi ^ ((row >> 1) & 3)) << 4));
}

// constant-index select for a dynamic lane of a floatx4 (avoids dynamic GEP)
__device__ __forceinline__ float vsel4(floatx4 v, int j) {
    return (j == 0) ? v[0] : (j == 1) ? v[1] : (j == 2) ? v[2] : v[3];
}

#define SBAR()  do { __builtin_amdgcn_sched_barrier(0); __builtin_amdgcn_s_barrier(); } while (0)
#define WAITV_(n) do { asm volatile("s_waitcnt vmcnt(" #n ")" ::: "memory"); \
                       __builtin_amdgcn_sched_barrier(0); } while (0)
#define WAITV(n) WAITV_(n)
#define WAITL_(n) do { asm volatile("s_waitcnt lgkmcnt(" #n ")" ::: "memory"); \
                       __builtin_amdgcn_sched_barrier(0); } while (0)
#define WAITL(n) WAITL_(n)

// 16-MFMA cluster on the CURRENT fragment set. All acc indices compile-time (rule #20).
#define MFMA_PH(AFR, BV0, BV1, NB) do { __builtin_amdgcn_s_setprio(1); \
    _Pragma("unroll") for (int m_ = 0; m_ < 8; ++m_) { \
        acc[m_][NB]     = __builtin_amdgcn_mfma_f32_16x16x32_bf16(AFR[m_], BV0, acc[m_][NB], 0, 0, 0); \
        acc[m_][NB + 1] = __builtin_amdgcn_mfma_f32_16x16x32_bf16(AFR[m_], BV1, acc[m_][NB + 1], 0, 0, 0); } \
    __builtin_amdgcn_s_setprio(0); } while (0)

// One K-tile = 4 phases. Cross-phase fragment pipeline: phase p issues the ds_reads for
// phase p+1's operands (alternate register set), then WAITL(n_issued) after the barrier so
// only the PREVIOUS phase's reads must be complete -> LDS pipe drains reads during MFMA.
//
// RACE RULE (round-3 lesson): a region's covering s_waitcnt vmcnt(N) must execute BEFORE
// an s_barrier, and the region's first ds_read AFTER that barrier — vmcnt is per-wave, so
// only the barrier makes "all waves retired their staging loads" true. Hence WAITV sits at
// the END of the phase PRECEDING the read, just before SBAR:
//   p0: [reads bB<-B0(T) n23][stage B1(T+1)][WAITV 8: retire A1(T),B1(T)][SBAR][WAITL 2][MFMA afr0 x bA][SBAR]
//   p1: [reads afr1<-A1(T), bA<-B1(T) n01][stage A0(T+2)]              [SBAR][WAITL 10][MFMA afr0 x bB][SBAR]
//   p2: [reads bB<-B1(T) n23][stage B0(T+2)][WAITV 8: retire A0/B0(T+1)][SBAR][WAITL 2][MFMA afr1 x bA][SBAR]
//   p3: [reads afr0<-A0(T+1), bA<-B0(T+1) n01][stage A1(T+2)]          [SBAR][WAITL 10][MFMA afr1 x bB][SBAR]
// vmcnt ledger (2 loads/stage, issue order B1(T+1),A0(T+2),B0(T+2),A1(T+2) per tile):
//   at p0 WAITV: outstanding<=12 {A1(T),B1(T),A0(T+1),B0(T+1),A1(T+1),B1(T+1)} -> 8 retires A1(T),B1(T)
//   at p2 WAITV: outstanding<=12 {A0(T+1)..B0(T+2)} -> 8 retires A0(T+1),B0(T+1)
// Overwrite hazards: each region's last reads lgkm-retire at the next phase's WAITL, >=1
// barrier before its overwriting stage is issued (checked per region).
#define TILE_BODY(T, W0, VM0, W2, VM2, S0, S1, S2, S3, R3) do { \
    const short* Ab  = As + (((T) & 1) * 2) * RSH; \
    const short* Bb  = Bs + (((T) & 1) * 2) * RSH; \
    const short* AbN = As + ((((T) + 1) & 1) * 2) * RSH; \
    const short* BbN = Bs + ((((T) + 1) & 1) * 2) * RSH; \
    /* p0 */ \
    bB0 = ldsfrag32(Bb, brow + 32, hi); \
    bB1 = ldsfrag32(Bb, brow + 48, hi); \
    if (S0) stage_region(Bop, Bs + ((((T) + 1) & 1) * 2 + 1) * RSH, w, l, ((T) + 1) * 64 + 32); \
    if (W0) WAITV(VM0); \
    SBAR(); WAITL(2); MFMA_PH(afr0, bA0, bA1, 0); SBAR(); \
    /* p1 */ \
    _Pragma("unroll") for (int m_ = 0; m_ < 8; ++m_) afr1[m_] = ldsfrag32(Ab + RSH, arow + m_ * 16, hi); \
    bA0 = ldsfrag32(Bb + RSH, brow + 0, hi); \
    bA1 = ldsfrag32(Bb + RSH, brow + 16, hi); \
    if (S1) stage_region(Aop, As + (((T) & 1) * 2 + 0) * RSH, w, l, ((T) + 2) * 64); \
    SBAR(); WAITL(10); MFMA_PH(afr0, bB0, bB1, 2); SBAR(); \
    /* p2 */ \
    bB0 = ldsfrag32(Bb + RSH, brow + 32, hi); \
    bB1 = ldsfrag32(Bb + RSH, brow + 48, hi); \
    if (S2) stage_region(Bop, Bs + (((T) & 1) * 2 + 0) * RSH, w, l, ((T) + 2) * 64); \
    if (W2) WAITV(VM2); \
    SBAR(); WAITL(2); MFMA_PH(afr1, bA0, bA1, 0); SBAR(); \
    /* p3 */ \
    if (R3) { \
        _Pragma("unroll") for (int m_ = 0; m_ < 8; ++m_) afr0[m_] = ldsfrag32(AbN, arow + m_ * 16, hi); \
        bA0 = ldsfrag32(BbN, brow + 0, hi); \
        bA1 = ldsfrag32(BbN, brow + 16, hi); \
    } \
    if (S3) stage_region(Aop, As + (((T) & 1) * 2 + 1) * RSH, w, l, ((T) + 2) * 64 + 32); \
    SBAR(); \
    if (R3) { WAITL(10); } else { WAITL(0); } \
    MFMA_PH(afr1, bB0, bB1, 2); SBAR(); \
} while (0)

// ---------------- fused 256^2 GEMM + per-tile partial LSE ----------------
// grid: 1280 blocks (16x16 tiles x 5 pairs), 512 threads (8 waves, 2M x 4N)
__launch_bounds__(512, 1)
__global__ void gemm_lse_kernel(const short* __restrict__ mats, const float* __restrict__ scale_p,
                                float* __restrict__ rowpart, float* __restrict__ colpart,
                                float* __restrict__ diag) {
    extern __shared__ char smem[];
    short* As = (short*)smem;                         // [2 buf][2 region][256][32]
    short* Bs = (short*)(smem + 65536);               // same
    float* rowLse = (float*)(smem + 131072);          // [4][256]
    float* colLse = rowLse + 4 * 256;                 // [2][256]

    const int tid = threadIdx.x;
    const int w = tid >> 6, l = tid & 63;
    const int wr = w >> 2, wc = w & 3;

    // bijective XCD swizzle: nwg = 1280 = 8 * 160
    const int orig = blockIdx.x;
    const int swz = (orig & 7) * 160 + (orig >> 3);
    const int p = swz >> 8;           // pair 0..4
    const int t = swz & 255;
    const int tileRow = t & 15, tileCol = t >> 4;

    // mats order: text(0) image(1) audio(2) depth(3); no stack arrays (rule #20)
    int ai, bi;
    switch (p) {
        case 0: ai = 2; bi = 0; break;
        case 1: ai = 2; bi = 1; break;
        case 2: ai = 3; bi = 0; break;
        case 3: ai = 3; bi = 1; break;
        default: ai = 0; bi = 1; break;
    }
    const short* Aop = mats + (size_t)ai * (BDIM * DDIM) + tileRow * 256 * DDIM;
    const short* Bop = mats + (size_t)bi * (BDIM * DDIM) + tileCol * 256 * DDIM;

    floatx4 acc[8][4];
#pragma unroll
    for (int m = 0; m < 8; ++m)
#pragma unroll
        for (int n = 0; n < 4; ++n) acc[m][n] = (floatx4)(0.f);

    const int fr = l & 15, hi = l >> 4;
    const int arow = wr * 128 + fr;   // + m*16
    const int brow = wc * 64 + fr;    // + n*16

    short8 afr0[8], afr1[8], bA0, bA1, bB0, bB1;

    // prologue: 7 regions (14 loads) in ledger order; retire A0(0),B0(0); BARRIER
    // (cross-wave visibility — round-3's missing barrier was the NaN); then pre-read
    // the first phase's operands. Those 10 reads retire at p0(0)'s WAITL(2).
    stage_region(Aop, As + 0 * RSH, w, l, 0);    // A0(0)
    stage_region(Bop, Bs + 0 * RSH, w, l, 0);    // B0(0)
    stage_region(Aop, As + 1 * RSH, w, l, 32);   // A1(0)
    stage_region(Bop, Bs + 1 * RSH, w, l, 32);   // B1(0)
    stage_region(Aop, As + 2 * RSH, w, l, 64);   // A0(1)
    stage_region(Bop, Bs + 2 * RSH, w, l, 64);   // B0(1)
    stage_region(Aop, As + 3 * RSH, w, l, 96);   // A1(1)
    WAITV(10);                                   // A0(0),B0(0) landed (own wave)
    SBAR();                                      // ...and for ALL waves
    {
#pragma unroll
        for (int m_ = 0; m_ < 8; ++m_) afr0[m_] = ldsfrag32(As, arow + m_ * 16, hi);
        bA0 = ldsfrag32(Bs, brow + 0, hi);
        bA1 = ldsfrag32(Bs, brow + 16, hi);
    }

#pragma unroll 2
    for (int kt = 0; kt < 14; ++kt) TILE_BODY(kt, 1, 8, 1, 8, 1, 1, 1, 1, 1);
    TILE_BODY(14, 1, 8, 1, 4, 1, 0, 0, 0, 1);
    TILE_BODY(15, 1, 0, 0, 0, 0, 0, 0, 0, 0);

    // scale (read AFTER the K-loop so no stray vector-mem op disturbs vmcnt counting)
    const float s = scale_p[0];
#pragma unroll
    for (int m = 0; m < 8; ++m)
#pragma unroll
        for (int n = 0; n < 4; ++n)
#pragma unroll
            for (int j = 0; j < 4; ++j) acc[m][n][j] *= s;

    // C/D layout: out[A-row: m*16+hi*4+j][B-row: n*16+fr] = acc[m][n][j]

    // ---- row partial LSE over this wave's 64 cols ----
#pragma unroll
    for (int m = 0; m < 8; ++m) {
#pragma unroll
        for (int j = 0; j < 4; ++j) {
            float mx = -3.0e38f;
#pragma unroll
            for (int n = 0; n < 4; ++n) mx = fmaxf(mx, acc[m][n][j]);
#pragma unroll
            for (int off = 1; off < 16; off <<= 1) mx = fmaxf(mx, __shfl_xor(mx, off));
            float sm = 0.f;
#pragma unroll
            for (int n = 0; n < 4; ++n) sm += __expf(acc[m][n][j] - mx);
#pragma unroll
            for (int off = 1; off < 16; off <<= 1) sm += __shfl_xor(sm, off);
            if (fr == 0)
                rowLse[wc * 256 + wr * 128 + m * 16 + hi * 4 + j] = mx + __logf(sm);
        }
    }

    // ---- col partial LSE over this wave's 128 rows ----
#pragma unroll
    for (int n = 0; n < 4; ++n) {
        float mx = -3.0e38f;
#pragma unroll
        for (int m = 0; m < 8; ++m)
#pragma unroll
            for (int j = 0; j < 4; ++j) mx = fmaxf(mx, acc[m][n][j]);
        mx = fmaxf(mx, __shfl_xor(mx, 16));
        mx = fmaxf(mx, __shfl_xor(mx, 32));
        float sm = 0.f;
#pragma unroll
        for (int m = 0; m < 8; ++m)
#pragma unroll
            for (int j = 0; j < 4; ++j) sm += __expf(acc[m][n][j] - mx);
        sm += __shfl_xor(sm, 16);
        sm += __shfl_xor(sm, 32);
        if (hi == 0)
            colLse[wr * 256 + wc * 64 + n * 16 + fr] = mx + __logf(sm);
    }

    // ---- diagonal: all acc[] array indices compile-time constant ----
    if (tileRow == tileCol && (wc >> 1) == wr) {
        if (hi == (fr >> 2)) {
            const int j = fr & 3;   // dynamic VECTOR lane only (select chain)
            float* dst = diag + p * BDIM + tileRow * 256 + wc * 64 + fr;
            if ((wc & 1) == 0) {
                dst[0]  = vsel4(acc[0][0], j);
                dst[16] = vsel4(acc[1][1], j);
                dst[32] = vsel4(acc[2][2], j);
                dst[48] = vsel4(acc[3][3], j);
            } else {
                dst[0]  = vsel4(acc[4][0], j);
                dst[16] = vsel4(acc[5][1], j);
                dst[32] = vsel4(acc[6][2], j);
                dst[48] = vsel4(acc[7][3], j);
            }
        }
    }

    __syncthreads();

    // combine partials: threads 0-255 rows, 256-511 cols
    if (tid < 256) {
        float v0 = rowLse[tid], v1 = rowLse[256 + tid], v2 = rowLse[512 + tid], v3 = rowLse[768 + tid];
        float mm = fmaxf(fmaxf(v0, v1), fmaxf(v2, v3));
        float r = mm + __logf(__expf(v0 - mm) + __expf(v1 - mm) + __expf(v2 - mm) + __expf(v3 - mm));
        rowpart[((size_t)p * BDIM + tileRow * 256 + tid) * TW + tileCol] = r;
    } else {
        int c = tid - 256;
        float v0 = colLse[c], v1 = colLse[256 + c];
        float mm = fmaxf(v0, v1);
        float r = mm + __logf(__expf(v0 - mm) + __expf(v1 - mm));
        colpart[((size_t)p * BDIM + tileCol * 256 + c) * TW + tileRow] = r;
    }
}

// ---------------- per-row final LSE + loss partial sums ----------------
__global__ void reduce_kernel(const float* __restrict__ rowpart, const float* __restrict__ colpart,
                              const float* __restrict__ diag, float* __restrict__ partials) {
    int p = blockIdx.y;
    int i = blockIdx.x * 256 + threadIdx.x;
    size_t gi = (size_t)p * BDIM + i;

    const float* rp = rowpart + gi * TW;
    float mx = -3.0e38f;
#pragma unroll
    for (int t = 0; t < TW; ++t) mx = fmaxf(mx, rp[t]);
    float sm = 0.f;
#pragma unroll
    for (int t = 0; t < TW; ++t) sm += __expf(rp[t] - mx);
    float rl = mx + __logf(sm);

    const float* cp = colpart + gi * TW;
    mx = -3.0e38f;
#pragma unroll
    for (int t = 0; t < TW; ++t) mx = fmaxf(mx, cp[t]);
    sm = 0.f;
#pragma unroll
    for (int t = 0; t < TW; ++t) sm += __expf(cp[t] - mx);
    float cl = mx + __logf(sm);

    float contrib = rl + cl - 2.f * diag[gi];

    __shared__ float red[256];
    red[threadIdx.x] = contrib;
    __syncthreads();
    for (int s2 = 128; s2 > 0; s2 >>= 1) {
        if (threadIdx.x < (unsigned)s2) red[threadIdx.x] += red[threadIdx.x + s2];
        __syncthreads();
    }
    if (threadIdx.x == 0) partials[p * 16 + blockIdx.x] = red[0];
}

__global__ void final_kernel(const float* __restrict__ partials, float* __restrict__ out) {
    __shared__ float red[128];
    int t = threadIdx.x;
    red[t] = (t < NPAIRS * 16) ? partials[t] : 0.f;
    __syncthreads();
    for (int s2 = 64; s2 > 0; s2 >>= 1) {
        if (t < s2) red[t] += red[t + s2];
        __syncthreads();
    }
    if (t == 0) out[0] = red[0] * (1.f / (2.f * BDIM));
}

extern "C" void kernel_launch(void* const* d_in, const int* in_sizes, int n_in,
                              void* d_out, int out_size, void* d_ws, size_t ws_size,
                              hipStream_t stream) {
    const float* text  = (const float*)d_in[0];
    const float* image = (const float*)d_in[1];
    const float* audio = (const float*)d_in[2];
    const float* depth = (const float*)d_in[3];
    const float* scale = (const float*)d_in[4];
    float* out = (float*)d_out;

    char* ws = (char*)d_ws;
    short* mats = (short*)ws;                                   // 4 * 8 MB bf16
    size_t off = (size_t)4 * BDIM * DDIM * 2;
    float* rowpart = (float*)(ws + off); off += (size_t)NPAIRS * BDIM * TW * 4;
    float* colpart = (float*)(ws + off); off += (size_t)NPAIRS * BDIM * TW * 4;
    float* diag    = (float*)(ws + off); off += (size_t)NPAIRS * BDIM * 4;
    float* partials= (float*)(ws + off); off += NPAIRS * 16 * 4;

    const int smem_bytes = 131072 + 4 * 256 * 4 + 2 * 256 * 4;  // 137216
    hipFuncSetAttribute((const void*)gemm_lse_kernel,
                        hipFuncAttributeMaxDynamicSharedMemorySize, smem_bytes);

    cast_kernel<<<dim3(2048, 4), 256, 0, stream>>>(text, image, audio, depth, mats);
    gemm_lse_kernel<<<dim3(1280), 512, smem_bytes, stream>>>(mats, scale, rowpart, colpart, diag);
    reduce_kernel<<<dim3(16, NPAIRS), 256, 0, stream>>>(rowpart, colpart, diag, partials);
    final_kernel<<<1, 128, 0, stream>>>(partials, out);
}